// Round 1
// baseline (67.678 us; speedup 1.0000x reference)
//
#include <hip/hip_runtime.h>
#include <math.h>

// Problem constants (match reference)
#define BB 2048
#define CC 1000
#define DD 64
constexpr float EPS_STATS = 1e-5f;
constexpr float EPS_PREC  = 1e-6f;
// counts.sum() = B + C*eps (reference sums fp32; difference negligible)
constexpr float TSUM = (float)BB + (float)CC * EPS_STATS;

// --- K1: accumulate per-class sums, sums-of-squares, integer counts ---
__global__ void k_accum(const float* __restrict__ z, const int* __restrict__ y,
                        float* __restrict__ sums, float* __restrict__ sumsq,
                        int* __restrict__ ncnt) {
    int g = blockIdx.x * blockDim.x + threadIdx.x;   // g in [0, B*D)
    if (g >= BB * DD) return;
    int b = g >> 6;          // D = 64
    int d = g & 63;
    int c = y[b];
    float v = z[g];          // coalesced: g is contiguous
    atomicAdd(&sums[c * DD + d], v);
    atomicAdd(&sumsq[c * DD + d], v * v);
    if (d == 0) atomicAdd(&ncnt[c], 1);
}

// --- K2: transposed class means (D x C) + log prior ---
__global__ void k_mean(const float* __restrict__ sums, const int* __restrict__ ncnt,
                       float* __restrict__ meanT, float* __restrict__ logpr) {
    int g = blockIdx.x * blockDim.x + threadIdx.x;   // g in [0, C*D)
    if (g >= CC * DD) return;
    int c = g >> 6;
    int d = g & 63;
    float ce = (float)ncnt[c] + EPS_STATS;
    float m = sums[g] / ce;
    meanT[d * CC + c] = m;   // scattered write; tiny array, L2-resident
    if (d == 0) logpr[c] = logf(ce / TSUM);
}

// --- K3: pooled diag covariance -> precision (single block, 256 threads) ---
// pooled[d] = (1/T) * sum_c [ sumsq - 2*m*sum + n*m^2 ] + EPS_STATS
__global__ void k_prec(const float* __restrict__ sums, const float* __restrict__ sumsq,
                       const int* __restrict__ ncnt, float* __restrict__ prec) {
    __shared__ float part[4][DD];
    int tid = threadIdx.x;
    int d = tid & 63;
    int chunk = tid >> 6;                 // 4 chunks of 250 classes
    float acc = 0.0f;
    int c0 = chunk * 250;
    for (int c = c0; c < c0 + 250; ++c) {
        float nn = (float)ncnt[c];
        float ce = nn + EPS_STATS;
        float s = sums[c * DD + d];       // lanes 0..63 -> coalesced row
        float q = sumsq[c * DD + d];
        float m = s / ce;
        acc += q - 2.0f * m * s + nn * m * m;
    }
    part[chunk][d] = acc;
    __syncthreads();
    if (tid < DD) {
        float pooled = (part[0][tid] + part[1][tid] + part[2][tid] + part[3][tid]) / TSUM
                       + EPS_STATS;
        prec[tid] = 1.0f / fmaxf(pooled, EPS_PREC);
    }
}

// --- K4: scoring. Block: 256 threads = 256 classes; 16 b-rows per block ---
#define ROWS 16
#define CTILE 256
__global__ void __launch_bounds__(256)
k_score(const float* __restrict__ z, const float* __restrict__ meanT,
        const float* __restrict__ prec, const float* __restrict__ logpr,
        float* __restrict__ out) {
    __shared__ float zs[ROWS][DD];   // 4 KB
    __shared__ float ps[DD];
    int tid = threadIdx.x;
    int b0 = blockIdx.x * ROWS;

    // load 16 rows of z (1024 floats) with 256 threads, coalesced
    #pragma unroll
    for (int i = 0; i < (ROWS * DD) / 256; ++i) {
        int idx = tid + i * 256;
        zs[idx >> 6][idx & 63] = z[b0 * DD + idx];
    }
    if (tid < DD) ps[tid] = prec[tid];
    __syncthreads();

    int c = blockIdx.y * CTILE + tid;
    int cc = (c < CC) ? c : (CC - 1);    // clamp for safe loads
    float logp = logpr[cc];

    float acc[ROWS];
    #pragma unroll
    for (int r = 0; r < ROWS; ++r) acc[r] = 0.0f;

    #pragma unroll 8
    for (int d = 0; d < DD; ++d) {
        float m = meanT[d * CC + cc];    // coalesced across lanes
        float p = ps[d];                 // LDS broadcast
        #pragma unroll
        for (int r = 0; r < ROWS; ++r) {
            float diff = zs[r][d] - m;   // LDS broadcast
            acc[r] = fmaf(p * diff, diff, acc[r]);
        }
    }

    if (c < CC) {
        #pragma unroll
        for (int r = 0; r < ROWS; ++r) {
            out[(size_t)(b0 + r) * CC + c] = logp - 0.5f * acc[r];
        }
    }
}

extern "C" void kernel_launch(void* const* d_in, const int* in_sizes, int n_in,
                              void* d_out, int out_size, void* d_ws, size_t ws_size,
                              hipStream_t stream) {
    const float* z = (const float*)d_in[0];
    const int*   y = (const int*)d_in[1];
    float* out = (float*)d_out;

    // ws layout (floats unless noted)
    float* sums  = (float*)d_ws;            // C*D = 64000
    float* sumsq = sums + CC * DD;          // 64000
    int*   ncnt  = (int*)(sumsq + CC * DD); // 1000 ints
    float* prec  = (float*)(ncnt + CC);     // 64
    float* meanT = prec + DD;               // D*C = 64000
    float* logpr = meanT + DD * CC;         // 1000

    // zero the accumulators (ws is poisoned; must zero every call)
    size_t zero_bytes = (size_t)(2 * CC * DD) * sizeof(float) + (size_t)CC * sizeof(int);
    hipMemsetAsync(d_ws, 0, zero_bytes, stream);

    k_accum<<<(BB * DD + 255) / 256, 256, 0, stream>>>(z, y, sums, sumsq, ncnt);
    k_mean <<<(CC * DD + 255) / 256, 256, 0, stream>>>(sums, ncnt, meanT, logpr);
    k_prec <<<1, 256, 0, stream>>>(sums, sumsq, ncnt, prec);

    dim3 grid(BB / ROWS, (CC + CTILE - 1) / CTILE);
    k_score<<<grid, 256, 0, stream>>>(z, meanT, prec, logpr, out);
}

// Round 2
// 65.530 us; speedup vs baseline: 1.0328x; 1.0328x over previous
//
#include <hip/hip_runtime.h>
#include <math.h>

// Problem constants (match reference)
#define BB 2048
#define CC 1000
#define DD 64
constexpr float EPS_STATS = 1e-5f;
constexpr float EPS_PREC  = 1e-6f;
// counts.sum() = B + C*eps (reference sums fp32; difference negligible)
constexpr float TSUM = (float)BB + (float)CC * EPS_STATS;

// --- K0: zero the accumulator region (runtime fillBuffer takes 40us; this ~2us) ---
__global__ void k_zero(float4* __restrict__ p, int n4) {
    int i = blockIdx.x * blockDim.x + threadIdx.x;
    if (i < n4) p[i] = float4{0.f, 0.f, 0.f, 0.f};
}

// --- K1: accumulate per-class sums, sums-of-squares, integer counts ---
__global__ void k_accum(const float* __restrict__ z, const int* __restrict__ y,
                        float* __restrict__ sums, float* __restrict__ sumsq,
                        int* __restrict__ ncnt) {
    int g = blockIdx.x * blockDim.x + threadIdx.x;   // g in [0, B*D)
    if (g >= BB * DD) return;
    int b = g >> 6;          // D = 64
    int d = g & 63;
    int c = y[b];
    float v = z[g];          // coalesced: g is contiguous
    atomicAdd(&sums[c * DD + d], v);
    atomicAdd(&sumsq[c * DD + d], v * v);
    if (d == 0) atomicAdd(&ncnt[c], 1);
}

// --- K2 (fused): blocks 0..249 -> transposed means + log prior;
//                 block 250     -> pooled diag covariance -> precision ---
__global__ void k_stats(const float* __restrict__ sums, const float* __restrict__ sumsq,
                        const int* __restrict__ ncnt,
                        float* __restrict__ meanT, float* __restrict__ logpr,
                        float* __restrict__ prec) {
    int tid = threadIdx.x;
    if (blockIdx.x < 250) {
        // 4 classes per block, 64 dims per class
        int g = blockIdx.x * 256 + tid;  // g in [0, C*D)
        int c = g >> 6;
        int d = g & 63;
        float ce = (float)ncnt[c] + EPS_STATS;
        float m = sums[g] / ce;
        meanT[d * CC + c] = m;   // scattered write; tiny array, L2-resident
        if (d == 0) logpr[c] = logf(ce / TSUM);
    } else {
        // pooled[d] = (1/T) * sum_c [ sumsq - 2*m*sum + n*m^2 ] + EPS_STATS
        __shared__ float part[4][DD];
        int d = tid & 63;
        int chunk = tid >> 6;                 // 4 chunks of 250 classes
        float acc = 0.0f;
        int c0 = chunk * 250;
        for (int c = c0; c < c0 + 250; ++c) {
            float nn = (float)ncnt[c];
            float ce = nn + EPS_STATS;
            float s = sums[c * DD + d];       // lanes 0..63 -> coalesced row
            float q = sumsq[c * DD + d];
            float m = s / ce;
            acc += q - 2.0f * m * s + nn * m * m;
        }
        part[chunk][d] = acc;
        __syncthreads();
        if (tid < DD) {
            float pooled = (part[0][tid] + part[1][tid] + part[2][tid] + part[3][tid]) / TSUM
                           + EPS_STATS;
            prec[tid] = 1.0f / fmaxf(pooled, EPS_PREC);
        }
    }
}

// --- K3: scoring. Block: 256 threads = 256 classes; 16 b-rows per block ---
#define ROWS 16
#define CTILE 256
__global__ void __launch_bounds__(256)
k_score(const float* __restrict__ z, const float* __restrict__ meanT,
        const float* __restrict__ prec, const float* __restrict__ logpr,
        float* __restrict__ out) {
    __shared__ float zs[ROWS][DD];   // 4 KB
    __shared__ float ps[DD];
    int tid = threadIdx.x;
    int b0 = blockIdx.x * ROWS;

    // load 16 rows of z (1024 floats) with 256 threads, coalesced
    #pragma unroll
    for (int i = 0; i < (ROWS * DD) / 256; ++i) {
        int idx = tid + i * 256;
        zs[idx >> 6][idx & 63] = z[b0 * DD + idx];
    }
    if (tid < DD) ps[tid] = prec[tid];
    __syncthreads();

    int c = blockIdx.y * CTILE + tid;
    int cc = (c < CC) ? c : (CC - 1);    // clamp for safe loads
    float logp = logpr[cc];

    float acc[ROWS];
    #pragma unroll
    for (int r = 0; r < ROWS; ++r) acc[r] = 0.0f;

    #pragma unroll 8
    for (int d = 0; d < DD; ++d) {
        float m = meanT[d * CC + cc];    // coalesced across lanes
        float p = ps[d];                 // LDS broadcast
        #pragma unroll
        for (int r = 0; r < ROWS; ++r) {
            float diff = zs[r][d] - m;   // LDS broadcast
            acc[r] = fmaf(p * diff, diff, acc[r]);
        }
    }

    if (c < CC) {
        #pragma unroll
        for (int r = 0; r < ROWS; ++r) {
            out[(size_t)(b0 + r) * CC + c] = logp - 0.5f * acc[r];
        }
    }
}

extern "C" void kernel_launch(void* const* d_in, const int* in_sizes, int n_in,
                              void* d_out, int out_size, void* d_ws, size_t ws_size,
                              hipStream_t stream) {
    const float* z = (const float*)d_in[0];
    const int*   y = (const int*)d_in[1];
    float* out = (float*)d_out;

    // ws layout (floats unless noted)
    float* sums  = (float*)d_ws;            // C*D = 64000
    float* sumsq = sums + CC * DD;          // 64000
    int*   ncnt  = (int*)(sumsq + CC * DD); // 1000 ints
    float* prec  = (float*)(ncnt + CC);     // 64
    float* meanT = prec + DD;               // D*C = 64000
    float* logpr = meanT + DD * CC;         // 1000

    // zero the accumulators ourselves (hipMemsetAsync's fill kernel cost 40us)
    int n4 = (2 * CC * DD + CC) / 4;        // 516000 B / 16 = 32250 float4's
    k_zero<<<(n4 + 255) / 256, 256, 0, stream>>>((float4*)d_ws, n4);

    k_accum<<<(BB * DD + 255) / 256, 256, 0, stream>>>(z, y, sums, sumsq, ncnt);
    k_stats<<<251, 256, 0, stream>>>(sums, sumsq, ncnt, meanT, logpr, prec);

    dim3 grid(BB / ROWS, (CC + CTILE - 1) / CTILE);
    k_score<<<grid, 256, 0, stream>>>(z, meanT, prec, logpr, out);
}